// Round 14
// baseline (231.485 us; speedup 1.0000x reference)
//
#include <hip/hip_runtime.h>

#define N_NODES 50000
#define N_EDGES 800000
#define CAP 48
#define PB_BLOCKS 2560
typedef _Float16 f16;
typedef _Float16 h2 __attribute__((ext_vector_type(2)));
typedef _Float16 h4 __attribute__((ext_vector_type(4)));
// IN_F = 64, OUT_F = 64, EDGE_F = 16, d_in1 = 144
// NOTE: harness passes ALL integer inputs as int32 — edge_index is int32[2*E],
// src = ei[e], dst = ei[E+e].
// NOTE (round 3): hipLaunchCooperativeKernel broke the harness. NEVER coop.
// NOTE (round 6): few hot global atomic counters = serialization disaster.
// NOTE (round 9): __shfl honors EXEC — stage must be ALL-LANES-ACTIVE with
// clamped index. readlane ignores exec.
// NOTE (round 10): 32-wide single-chain stage = bank conflicts + VGPR
// serialization. 16-deep contiguous stage (byte 8*j / 16*j) is proven.
// NOTE (rounds 11/13): FETCH 183->135->100MB with dur 83->76->74 ->
// nodefused is DEPENDENT-LATENCY-bound (no pipe saturated; 4.6x above BW
// floor). Round 14: TWO nodes per wave with interleaved chains (slotA||slotB
// -> stageA||stageB -> gathersA||gathersB -> consumeA -> consumeB); slot
// loads unconditionally (stale tail entries never read via clamp) to break
// the false cnt->slot dependency; W2 epilogue loads amortized over 2 nodes.

#if defined(__has_builtin) && __has_builtin(__builtin_amdgcn_fdot2)
#define FDOT2(a, b, c) __builtin_amdgcn_fdot2((a), (b), (c), false)
#else
#define FDOT2(a, b, c) ((c) + (float)(a)[0] * (float)(b)[0] + (float)(a)[1] * (float)(b)[1])
#endif

// ---------------------------------------------------------------------------
// prebuild_kernel: EVERY block does
//   (1) build chunk: grid-stride over edges, bucket e by dst: slot=(src,e)
//   (2) pre chunk: xa = x @ W1[0:64,:] (fp16), xb = x @ W1[64:128,:] (fp32)
//       per-lane coalesced x load -> per-wave LDS row -> broadcast
//       ds_read_b128; next row software-pipelined; 4 accumulator chains.
// cnt/ocnt must be zeroed before launch (memsetAsync).
// ---------------------------------------------------------------------------
__global__ __launch_bounds__(256) void prebuild_kernel(
    const float* __restrict__ x, const float* __restrict__ W1,
    f16* __restrict__ xa, float* __restrict__ xb,
    const int* __restrict__ ei, unsigned* __restrict__ cnt,
    unsigned* __restrict__ ocnt, uint2* __restrict__ slot,
    unsigned* __restrict__ oflow)
{
    __shared__ __align__(16) float srow[4][64];   // per-wave x-row buffer

    const int tid = threadIdx.x;
    const int bid = blockIdx.x;

    // ---- build part: bucket edges by dst; slot holds (src, edge) 8 B ----
    for (int e = bid * 256 + tid; e < N_EDGES; e += PB_BLOCKS * 256) {
        const int s = ei[e];
        const int d = ei[N_EDGES + e];
        const unsigned pos = atomicAdd(&cnt[d], 1u);
        if (pos < CAP) {
            slot[(size_t)d * CAP + pos] = make_uint2((unsigned)s, (unsigned)e);
        } else {
            const unsigned oi = atomicAdd(ocnt, 1u);
            oflow[oi] = (unsigned)e;
        }
    }

    // ---- pre part: wave per (node-subset, product) ----
    const int w = tid >> 6;
    const int j = tid & 63;
    const int gw = bid * 4 + w;
    const int p = gw & 1;              // 0 -> xa (f16), 1 -> xb (f32)
    const int pair = gw >> 1;
    const int npair = PB_BLOCKS * 2;   // 5120

    float wc[64];
#pragma unroll
    for (int k = 0; k < 64; ++k) wc[k] = W1[(p * 64 + k) * 64 + j];

    if (pair < N_NODES) {
        float xv = x[(size_t)pair * 64 + j];          // pipelined row element
        for (int i = pair; i < N_NODES; i += npair) {
            srow[w][j] = xv;                           // wave-internal LDS write
            const int inext = i + npair;
            float xnext = 0.f;
            if (inext < N_NODES) xnext = x[(size_t)inext * 64 + j];

            float a0 = 0.f, a1 = 0.f, a2 = 0.f, a3 = 0.f;
#pragma unroll
            for (int k4 = 0; k4 < 4; ++k4) {
                const float4 v0 = *(const float4*)&srow[w][k4 * 16 + 0];
                const float4 v1 = *(const float4*)&srow[w][k4 * 16 + 4];
                const float4 v2 = *(const float4*)&srow[w][k4 * 16 + 8];
                const float4 v3 = *(const float4*)&srow[w][k4 * 16 + 12];
                a0 += v0.x * wc[k4 * 16 + 0];  a0 += v0.y * wc[k4 * 16 + 1];
                a0 += v0.z * wc[k4 * 16 + 2];  a0 += v0.w * wc[k4 * 16 + 3];
                a1 += v1.x * wc[k4 * 16 + 4];  a1 += v1.y * wc[k4 * 16 + 5];
                a1 += v1.z * wc[k4 * 16 + 6];  a1 += v1.w * wc[k4 * 16 + 7];
                a2 += v2.x * wc[k4 * 16 + 8];  a2 += v2.y * wc[k4 * 16 + 9];
                a2 += v2.z * wc[k4 * 16 + 10]; a2 += v2.w * wc[k4 * 16 + 11];
                a3 += v3.x * wc[k4 * 16 + 12]; a3 += v3.y * wc[k4 * 16 + 13];
                a3 += v3.z * wc[k4 * 16 + 14]; a3 += v3.w * wc[k4 * 16 + 15];
            }
            const float val = (a0 + a1) + (a2 + a3);
            if (p) xb[(size_t)i * 64 + j] = val;          // wave-uniform branch
            else   xa[(size_t)i * 64 + j] = (f16)val;
            xv = xnext;
        }
    }
}

// ---------------------------------------------------------------------------
// nodefused_kernel: one wave per TWO dst nodes (nA = gw, nB = gw + 25000).
//   hacc = sum_e relu(xa[src]+xb[n]+ea@W1c+b1); out = hacc@W2 + deg*b2
// Interleaved independent chains: slotA||slotB -> stageA||stageB ->
// gathersA||gathersB -> consumeA -> consumeB. B's latency hides under A's
// compute. W2 epilogue loads shared by both nodes. Grid = N_NODES/8 blocks.
// ---------------------------------------------------------------------------
__global__ __launch_bounds__(256) void nodefused_kernel(
    const f16* __restrict__ xa, const float* __restrict__ xb,
    const float* __restrict__ ea, const uint2* __restrict__ slot,
    const int* __restrict__ ei, const unsigned* __restrict__ cnt,
    const float* __restrict__ W1, const float* __restrict__ b1,
    const float* __restrict__ W2, const float* __restrict__ b2,
    const unsigned* __restrict__ ocnt, const unsigned* __restrict__ oflow,
    float* __restrict__ out)
{
    __shared__ __align__(16) f16   sea[4][2][CAP * 16];   // 12 KB
    __shared__ __align__(16) float sh[4][2][64];          // 2 KB

    const int w = threadIdx.x >> 6;
    const int j = threadIdx.x & 63;
    const int gw = blockIdx.x * 4 + w;
    const int nA = gw;
    const int nB = gw + N_NODES / 2;

    // W1c column j as 8 f16 pairs (for dot2)
    h2 w1h[8];
#pragma unroll
    for (int r = 0; r < 8; ++r) {
        w1h[r][0] = (f16)W1[(128 + 2 * r) * 64 + j];
        w1h[r][1] = (f16)W1[(128 + 2 * r + 1) * 64 + j];
    }
    const float b1j = b1[j];
    const float b2j = b2[j];

    // slot loads issued UNCONDITIONALLY on j<CAP (stale tail entries are
    // never read: clamped shfl/readlane only touch lanes < dcap). This
    // breaks the cnt->slot dependency; cnt loads fly in parallel.
    uint2 myA = make_uint2(0u, 0u), myB = make_uint2(0u, 0u);
    if (j < CAP) {
        myA = slot[(size_t)nA * CAP + j];
        myB = slot[(size_t)nB * CAP + j];
    }
    const int degA = (int)cnt[nA];
    const int degB = (int)cnt[nB];
    const int dcapA = degA < CAP ? degA : CAP;
    const int dcapB = degB < CAP ? degB : CAP;
    const int svA = (int)myA.x, evA = (int)myA.y;
    const int svB = (int)myB.x, evB = (int)myB.y;

    const float baseA = xb[(size_t)nA * 64 + j] + b1j;
    const float baseB = xb[(size_t)nB * 64 + j] + b1j;

    const int sub = j >> 2;        // which edge of the chunk this lane stages
    const int q   = j & 3;         // which 4-float quarter of that edge

    float hA = 0.f, hB = 0.f;
    const int mcap = dcapA > dcapB ? dcapA : dcapB;

    for (int b0 = 0; b0 < mcap; b0 += 16) {
        // ---- stage ea chunks (f32 -> f16 LDS), ALL-lanes clamped (r9) ----
        if (b0 < dcapA) {                                // wave-uniform guard
            int ii = b0 + sub;
            const int ic = ii < dcapA ? ii : dcapA - 1;  // clamp: benign dup
            const unsigned eid = (unsigned)__shfl(evA, ic);
            float4 v = *(const float4*)(ea + (size_t)eid * 16 + q * 4);
            h4 pv = {(f16)v.x, (f16)v.y, (f16)v.z, (f16)v.w};
            *(h4*)&sea[w][0][ic * 16 + q * 4] = pv;
        }
        if (b0 < dcapB) {
            int ii = b0 + sub;
            const int ic = ii < dcapB ? ii : dcapB - 1;
            const unsigned eid = (unsigned)__shfl(evB, ic);
            float4 v = *(const float4*)(ea + (size_t)eid * 16 + q * 4);
            h4 pv = {(f16)v.x, (f16)v.y, (f16)v.z, (f16)v.w};
            *(h4*)&sea[w][1][ic * 16 + q * 4] = pv;
        }
        // ---- issue both gather sets (static indexing, readlane-safe) ----
        float xvA[16];
        if (b0 < dcapA) {
#pragma unroll
            for (int t = 0; t < 16; ++t) {
                int ii = b0 + t;
                const int ic = ii < dcapA ? ii : dcapA - 1;
                const unsigned ss = (unsigned)__builtin_amdgcn_readlane(svA, ic);
                xvA[t] = (float)xa[(size_t)ss * 64 + j];
            }
        }
        float xvB[16];
        if (b0 < dcapB) {
#pragma unroll
            for (int t = 0; t < 16; ++t) {
                int ii = b0 + t;
                const int ic = ii < dcapB ? ii : dcapB - 1;
                const unsigned ss = (unsigned)__builtin_amdgcn_readlane(svB, ic);
                xvB[t] = (float)xa[(size_t)ss * 64 + j];
            }
        }
        // ---- consume A then B (B's loads finished under A's compute) ----
        if (b0 < dcapA) {
#pragma unroll
            for (int t = 0; t < 16; ++t) {
                const int ii = b0 + t;
                if (ii < dcapA) {                        // wave-uniform
                    uint4 r0 = *(const uint4*)&sea[w][0][ii * 16];
                    uint4 r1 = *(const uint4*)&sea[w][0][ii * 16 + 8];
                    float acc = baseA + xvA[t];
                    acc = FDOT2(__builtin_bit_cast(h2, r0.x), w1h[0], acc);
                    acc = FDOT2(__builtin_bit_cast(h2, r0.y), w1h[1], acc);
                    acc = FDOT2(__builtin_bit_cast(h2, r0.z), w1h[2], acc);
                    acc = FDOT2(__builtin_bit_cast(h2, r0.w), w1h[3], acc);
                    acc = FDOT2(__builtin_bit_cast(h2, r1.x), w1h[4], acc);
                    acc = FDOT2(__builtin_bit_cast(h2, r1.y), w1h[5], acc);
                    acc = FDOT2(__builtin_bit_cast(h2, r1.z), w1h[6], acc);
                    acc = FDOT2(__builtin_bit_cast(h2, r1.w), w1h[7], acc);
                    hA += fmaxf(acc, 0.f);
                }
            }
        }
        if (b0 < dcapB) {
#pragma unroll
            for (int t = 0; t < 16; ++t) {
                const int ii = b0 + t;
                if (ii < dcapB) {
                    uint4 r0 = *(const uint4*)&sea[w][1][ii * 16];
                    uint4 r1 = *(const uint4*)&sea[w][1][ii * 16 + 8];
                    float acc = baseB + xvB[t];
                    acc = FDOT2(__builtin_bit_cast(h2, r0.x), w1h[0], acc);
                    acc = FDOT2(__builtin_bit_cast(h2, r0.y), w1h[1], acc);
                    acc = FDOT2(__builtin_bit_cast(h2, r0.z), w1h[2], acc);
                    acc = FDOT2(__builtin_bit_cast(h2, r0.w), w1h[3], acc);
                    acc = FDOT2(__builtin_bit_cast(h2, r1.x), w1h[4], acc);
                    acc = FDOT2(__builtin_bit_cast(h2, r1.y), w1h[5], acc);
                    acc = FDOT2(__builtin_bit_cast(h2, r1.z), w1h[6], acc);
                    acc = FDOT2(__builtin_bit_cast(h2, r1.w), w1h[7], acc);
                    hB += fmaxf(acc, 0.f);
                }
            }
        }
    }

    // ---- overflow folds (wave-uniform gates; expected never taken) ----
    if (degA > CAP) {
        const unsigned oc = *ocnt;
        for (unsigned t2 = 0; t2 < oc; ++t2) {
            const int e = (int)oflow[t2];
            if (ei[N_EDGES + e] == nA) {
                const int s = ei[e];
                float acc = baseA + (float)xa[(size_t)s * 64 + j];
                for (int k = 0; k < 16; ++k)
                    acc += ea[(size_t)e * 16 + k] * W1[(128 + k) * 64 + j];
                hA += fmaxf(acc, 0.f);
            }
        }
    }
    if (degB > CAP) {
        const unsigned oc = *ocnt;
        for (unsigned t2 = 0; t2 < oc; ++t2) {
            const int e = (int)oflow[t2];
            if (ei[N_EDGES + e] == nB) {
                const int s = ei[e];
                float acc = baseB + (float)xa[(size_t)s * 64 + j];
                for (int k = 0; k < 16; ++k)
                    acc += ea[(size_t)e * 16 + k] * W1[(128 + k) * 64 + j];
                hB += fmaxf(acc, 0.f);
            }
        }
    }

    // ---- fused epilogue: shared W2 loads for both nodes ----
    sh[w][0][j] = hA;
    sh[w][1][j] = hB;
    float msgA = (float)degA * b2j;
    float msgB = (float)degB * b2j;
#pragma unroll
    for (int k4 = 0; k4 < 16; ++k4) {
        float4 ha4 = *(const float4*)&sh[w][0][k4 * 4];     // uniform broadcast
        float4 hb4 = *(const float4*)&sh[w][1][k4 * 4];
        const float w0 = W2[(k4 * 4 + 0) * 64 + j];
        const float w1 = W2[(k4 * 4 + 1) * 64 + j];
        const float w2v = W2[(k4 * 4 + 2) * 64 + j];
        const float w3 = W2[(k4 * 4 + 3) * 64 + j];
        msgA += ha4.x * w0; msgB += hb4.x * w0;
        msgA += ha4.y * w1; msgB += hb4.y * w1;
        msgA += ha4.z * w2v; msgB += hb4.z * w2v;
        msgA += ha4.w * w3; msgB += hb4.w * w3;
    }
    out[(size_t)nA * 64 + j] = msgA;
    out[(size_t)nB * 64 + j] = msgB;
}

// ---------------------------------------------------------------------------
// OLD PATH kernels (ws too small for bucketed pipeline) — fp32 throughout
// ---------------------------------------------------------------------------
__global__ __launch_bounds__(256) void pre_kernel(
    const float* __restrict__ x, const float* __restrict__ W1,
    float* __restrict__ xa, float* __restrict__ xb)
{
    const int w = threadIdx.x >> 6;
    const int j = threadIdx.x & 63;
    const int gw = blockIdx.x * 4 + w;
    const int p = gw & 1;
    const int pair = gw >> 1;
    const int npair = (gridDim.x * 4) >> 1;

    float wc[64];
#pragma unroll
    for (int k = 0; k < 64; ++k) wc[k] = W1[(p * 64 + k) * 64 + j];
    float* __restrict__ outp = p ? xb : xa;
    for (int i = pair; i < N_NODES; i += npair) {
        const float4* xr = (const float4*)&x[(size_t)i * 64];
        float acc = 0.f;
#pragma unroll
        for (int k4 = 0; k4 < 16; ++k4) {
            float4 xv = xr[k4];
            acc += xv.x * wc[k4 * 4 + 0];
            acc += xv.y * wc[k4 * 4 + 1];
            acc += xv.z * wc[k4 * 4 + 2];
            acc += xv.w * wc[k4 * 4 + 3];
        }
        outp[(size_t)i * 64 + j] = acc;
    }
}

__global__ __launch_bounds__(256) void edge_kernel(
    const float* __restrict__ xa, const float* __restrict__ xb,
    const int* __restrict__ ei,
    const float* __restrict__ edge_attr,
    const float* __restrict__ W1, const float* __restrict__ b1,
    const float* __restrict__ W2, const float* __restrict__ b2,
    float* __restrict__ out)
{
    __shared__ __align__(16) float eas[4][256];
    __shared__ __align__(16) float hs[4][16][64];

    const int w = threadIdx.x >> 6;
    const int j = threadIdx.x & 63;
    const int wt = blockIdx.x * 4 + w;
    const long eb = (long)wt * 16;

    float w1c[16];
    float w2c[64];
#pragma unroll
    for (int k = 0; k < 16; ++k) w1c[k] = W1[(128 + k) * 64 + j];
#pragma unroll
    for (int k = 0; k < 64; ++k) w2c[k] = W2[k * 64 + j];
    const float b1j = b1[j];
    const float b2j = b2[j];

    int idxv = 0;
    if (j < 16)       idxv = ei[eb + j];
    else if (j < 32)  idxv = ei[(long)N_EDGES + eb + (j - 16)];

    {
        float4 ev = *(const float4*)&edge_attr[eb * 16 + j * 4];
        *(float4*)&eas[w][j * 4] = ev;
    }

#pragma unroll 4
    for (int e = 0; e < 16; ++e) {
        const int s  = __shfl(idxv, e);
        const int dd = __shfl(idxv, 16 + e);

        float acc = xa[(long)s * 64 + j] + xb[(long)dd * 64 + j] + b1j;
#pragma unroll
        for (int k4 = 0; k4 < 4; ++k4) {
            float4 ev = *(const float4*)&eas[w][e * 16 + k4 * 4];
            acc += ev.x * w1c[k4 * 4 + 0];
            acc += ev.y * w1c[k4 * 4 + 1];
            acc += ev.z * w1c[k4 * 4 + 2];
            acc += ev.w * w1c[k4 * 4 + 3];
        }
        const float h = fmaxf(acc, 0.f);
        hs[w][e][j] = h;

        float msg = b2j;
#pragma unroll
        for (int k4 = 0; k4 < 16; ++k4) {
            float4 hv = *(const float4*)&hs[w][e][k4 * 4];
            msg += hv.x * w2c[k4 * 4 + 0];
            msg += hv.y * w2c[k4 * 4 + 1];
            msg += hv.z * w2c[k4 * 4 + 2];
            msg += hv.w * w2c[k4 * 4 + 3];
        }
        unsafeAtomicAdd(&out[(long)dd * 64 + j], msg);
    }
}

__global__ __launch_bounds__(256) void fallback_kernel(
    const float* __restrict__ x, const int* __restrict__ ei,
    const float* __restrict__ edge_attr,
    const float* __restrict__ W1, const float* __restrict__ b1,
    const float* __restrict__ W2, const float* __restrict__ b2,
    float* __restrict__ out)
{
    const int w = threadIdx.x >> 6;
    const int j = threadIdx.x & 63;
    const long e = (long)blockIdx.x * 4 + w;
    if (e >= N_EDGES) return;
    const int s  = ei[e];
    const int dd = ei[(long)N_EDGES + e];

    float acc = b1[j];
    for (int k = 0; k < 64; ++k) acc += x[(long)s  * 64 + k] * W1[k * 64 + j];
    for (int k = 0; k < 64; ++k) acc += x[(long)dd * 64 + k] * W1[(64 + k) * 64 + j];
    for (int k = 0; k < 16; ++k) acc += edge_attr[e * 16 + k] * W1[(128 + k) * 64 + j];
    const float h = fmaxf(acc, 0.f);

    float msg = b2[j];
    for (int k = 0; k < 64; ++k) msg += __shfl(h, k) * W2[k * 64 + j];
    unsafeAtomicAdd(&out[(long)dd * 64 + j], msg);
}

extern "C" void kernel_launch(void* const* d_in, const int* in_sizes, int n_in,
                              void* d_out, int out_size, void* d_ws, size_t ws_size,
                              hipStream_t stream) {
    const float* x   = (const float*)d_in[0];
    const int*   ei  = (const int*)d_in[1];
    const float* ea  = (const float*)d_in[2];
    const float* W1  = (const float*)d_in[3];
    const float* b1  = (const float*)d_in[4];
    const float* W2  = (const float*)d_in[5];
    const float* b2  = (const float*)d_in[6];
    float* out = (float*)d_out;

    const size_t NF = (size_t)N_NODES * 64;
    const size_t need_main = NF * 2 + NF * 4               // xa (f16), xb (f32)
                           + (size_t)N_NODES * 4 + 256     // cnt, ocnt(+pad)
                           + (size_t)N_NODES * CAP * 8     // slot (uint2)
                           + (size_t)N_EDGES * 4;          // oflow
    const size_t need_old = 2 * NF * 4;

    if (ws_size >= need_main) {
        char* p = (char*)d_ws;
        f16*      xauf  = (f16*)p;      p += NF * 2;
        float*    xbuf  = (float*)p;    p += NF * 4;
        unsigned* cnt   = (unsigned*)p; p += (size_t)N_NODES * 4;
        unsigned* ocnt  = (unsigned*)p; p += 256;
        uint2*    slot  = (uint2*)p;    p += (size_t)N_NODES * CAP * 8;
        unsigned* oflow = (unsigned*)p;

        hipMemsetAsync(cnt, 0, (size_t)N_NODES * 4 + 256, stream);
        prebuild_kernel<<<PB_BLOCKS, 256, 0, stream>>>(
            x, W1, xauf, xbuf, ei, cnt, ocnt, slot, oflow);
        nodefused_kernel<<<N_NODES / 8, 256, 0, stream>>>(
            xauf, xbuf, ea, slot, ei, cnt, W1, b1, W2, b2, ocnt, oflow, out);
    } else if (ws_size >= need_old) {
        hipMemsetAsync(out, 0, (size_t)N_NODES * 64 * sizeof(float), stream);
        float* xauf = (float*)d_ws;
        float* xbuf = xauf + NF;
        pre_kernel<<<512, 256, 0, stream>>>(x, W1, xauf, xbuf);
        edge_kernel<<<N_EDGES / 64, 256, 0, stream>>>(xauf, xbuf, ei, ea,
                                                      W1, b1, W2, b2, out);
    } else {
        hipMemsetAsync(out, 0, (size_t)N_NODES * 64 * sizeof(float), stream);
        fallback_kernel<<<N_EDGES / 4, 256, 0, stream>>>(x, ei, ea,
                                                         W1, b1, W2, b2, out);
    }
}